// Round 6
// baseline (143.665 us; speedup 1.0000x reference)
//
#include <hip/hip_runtime.h>
#include <math.h>

// Problem constants (reference: N=64, H=512, W=512, RATIO=2, ITERATIONS=1)
#define NIMG 64
#define HH 512
#define WW 512
#define TR 16                          // output rows per block
#define LR (TR + 2)                    // staged rows incl. vertical halo = 18
#define LSTRIDE 130                    // u32 per LDS row: 128 data + 2 pad cols
#define NBLOCKS (NIMG * (HH / TR))     // 64*32 = 2048
#define INV_TOTAL (1.0f / 16777216.0f) // 1/(64*512*512), exact pow2

typedef unsigned int u32;
typedef unsigned long long u64;

// Flag byte per pixel: bit0 = (y>0), bit1 = (y==0), 0x00 = invalid/halo.
// cv2-clipped-border morphology: border = has_one & has_zero over the valid
// 3x3 window; invalid cells contribute to NEITHER bit (0x00 sentinel).
__device__ __forceinline__ u32 flags4(int4 yv) {
    u32 f = (yv.x > 0) ? 1u : 2u;
    f |= ((yv.y > 0) ? 1u : 2u) << 8;
    f |= ((yv.z > 0) ? 1u : 2u) << 16;
    f |= ((yv.w > 0) ? 1u : 2u) << 24;
    return f;
}

__global__ __launch_bounds__(256, 6) void border_loss_main(
    const float* __restrict__ x, const int* __restrict__ y,
    float* __restrict__ part, int atomic_mode)
{
    __shared__ __align__(16) u32 flags[LR][LSTRIDE];   // 18*130*4 = 9360 B
    __shared__ float wsum[4];

    const int tid  = threadIdx.x;
    const int lane = tid & 63;
    const int wv   = tid >> 6;               // wave 0..3
    const int b    = blockIdx.x;
    const int n    = b >> 5;                 // image (32 strips/image)
    const int R0   = (b & 31) * TR;          // first output row of strip
    const int base = n * (HH * WW);          // < 2^24, int-safe
    const int*   __restrict__ yb = y + base;
    const float* __restrict__ xb = x + base;

    const int h = tid >> 7;                  // 0/1, wave-uniform
    const int g = tid & 127;                 // u32 group within row

    // ---- zero the pad columns (sentinel = invalid)
    if (tid < 2 * LR) {
        flags[tid >> 1][(tid & 1) ? (LSTRIDE - 1) : 0] = 0u;
    }

    // ---- Phase 1: batched y loads, LDS rows j = h + 2*it (it = 0..8).
    // All 9 int4 loads issued back-to-back (clamped rows, no branches),
    // then convert+store drains them with fine-grained vmcnt.
#define YROW(it) (R0 - 1 + h + 2 * (it))
#define YCLAMP(it) (((unsigned)YROW(it) < (unsigned)HH) ? YROW(it) \
                    : ((YROW(it) < 0) ? 0 : (HH - 1)))
#define YLD(it) const int4 yv##it = *(const int4*)(yb + YCLAMP(it) * WW + (g << 2));
    YLD(0) YLD(1) YLD(2) YLD(3) YLD(4) YLD(5) YLD(6) YLD(7) YLD(8)
#define YST(it) flags[h + 2 * (it)][g + 1] = \
        ((unsigned)YROW(it) < (unsigned)HH) ? flags4(yv##it) : 0u;
    YST(0) YST(1) YST(2) YST(3) YST(4) YST(5) YST(6) YST(7) YST(8)
#undef YLD
#undef YST
#undef YCLAMP
#undef YROW

    // ---- Prefetch x for phase-2 iterations 0,1 BEFORE the barrier.
    // Wave wv handles rows wv + 4*it, lane owns 8-px chunk = cols 8*lane..+7.
    const float* xr = xb + (R0 + wv) * WW + (lane << 3);
    const float4 xa0 = *(const float4*)(xr);
    const float4 xd0 = *(const float4*)(xr + 4);
    const float4 xa1 = *(const float4*)(xr + 4 * WW);
    const float4 xd1 = *(const float4*)(xr + 4 * WW + 4);

    __syncthreads();

    const float4 xa2 = *(const float4*)(xr + 8 * WW);
    const float4 xd2 = *(const float4*)(xr + 8 * WW + 4);

    float acc = 0.0f;
    const int d = lane << 1;                 // pad-dword index of left word

    // per-pixel: max(x,0) - x*m + ln(1+e^{-|x|}); weight 2 on border bits
#define PX(xf, sh) { \
        const float lg = __logf(1.0f + __expf(-fabsf(xf))); \
        const float ls = fmaxf(xf, 0.0f) - (((m64 >> (sh)) & 1ull) ? (xf) : 0.0f) + lg; \
        acc = fmaf(ls, ((border >> (sh)) & 1ull) ? 2.0f : 1.0f, acc); \
    }
#define COMP(it, xa, xd) { \
        const int jt = wv + 4 * (it); \
        const u64 t0 = *(const u64*)&flags[jt    ][d]; \
        const u64 t1 = *(const u64*)&flags[jt    ][d + 2]; \
        const u64 c0 = *(const u64*)&flags[jt + 1][d]; \
        const u64 c1 = *(const u64*)&flags[jt + 1][d + 2]; \
        const u64 b0 = *(const u64*)&flags[jt + 2][d]; \
        const u64 b1 = *(const u64*)&flags[jt + 2][d + 2]; \
        const u64 A = t0 | c0 | b0;          /* cols 8c-4 .. 8c+3  */ \
        const u64 B = t1 | c1 | b1;          /* cols 8c+4 .. 8c+11 */ \
        const u64 cen = (A >> 32) | (B << 32); \
        const u64 lb  = (A >> 24) & 0xffull; \
        const u64 rb  = ((B >> 32) & 0xffull) << 56; \
        const u64 hh  = cen | (cen << 8) | (cen >> 8) | lb | rb; \
        const u64 border = hh & (hh >> 1) & 0x0101010101010101ull; \
        const u64 m64    = (c0 >> 32) | (c1 << 32); \
        PX(xa.x,  0) PX(xa.y,  8) PX(xa.z, 16) PX(xa.w, 24) \
        PX(xd.x, 32) PX(xd.y, 40) PX(xd.z, 48) PX(xd.w, 56) \
    }

    COMP(0, xa0, xd0)
    const float4 xa3 = *(const float4*)(xr + 12 * WW);
    const float4 xd3 = *(const float4*)(xr + 12 * WW + 4);
    COMP(1, xa1, xd1)
    COMP(2, xa2, xd2)
    COMP(3, xa3, xd3)
#undef COMP
#undef PX

    // ---- reduction: wave shuffle + tiny LDS across 4 waves
    #pragma unroll
    for (int off = 32; off > 0; off >>= 1)
        acc += __shfl_down(acc, off);
    __syncthreads();                         // flags tile dead; reuse barrier
    if (lane == 0) wsum[wv] = acc;
    __syncthreads();
    if (tid == 0) {
        const float t = wsum[0] + wsum[1] + wsum[2] + wsum[3];
        if (atomic_mode) atomicAdd(part, t * INV_TOTAL);
        else             part[blockIdx.x] = t;
    }
}

__global__ __launch_bounds__(256) void border_loss_reduce(
    const float* __restrict__ part, float* __restrict__ out)
{
    __shared__ float wsum[4];
    float t = 0.0f;
    for (int i = threadIdx.x; i < NBLOCKS; i += 256) t += part[i];
    #pragma unroll
    for (int off = 32; off > 0; off >>= 1)
        t += __shfl_down(t, off);
    if ((threadIdx.x & 63) == 0) wsum[threadIdx.x >> 6] = t;
    __syncthreads();
    if (threadIdx.x == 0)
        out[0] = (wsum[0] + wsum[1] + wsum[2] + wsum[3]) * INV_TOTAL;
}

__global__ void border_loss_zero(float* out) { out[0] = 0.0f; }

extern "C" void kernel_launch(void* const* d_in, const int* in_sizes, int n_in,
                              void* d_out, int out_size, void* d_ws, size_t ws_size,
                              hipStream_t stream)
{
    const float* x = (const float*)d_in[0];
    const int*   y = (const int*)d_in[1];
    float* out = (float*)d_out;

    if (ws_size >= (size_t)NBLOCKS * sizeof(float)) {
        // Deterministic two-stage reduction via workspace partials.
        float* part = (float*)d_ws;
        border_loss_main<<<NBLOCKS, 256, 0, stream>>>(x, y, part, 0);
        border_loss_reduce<<<1, 256, 0, stream>>>(part, out);
    } else {
        // Fallback: zero output then atomic accumulation.
        border_loss_zero<<<1, 1, 0, stream>>>(out);
        border_loss_main<<<NBLOCKS, 256, 0, stream>>>(x, y, out, 1);
    }
}